// Round 1
// baseline (142.551 us; speedup 1.0000x reference)
//
#include <hip/hip_runtime.h>
#include <cmath>

// Problem constants (fixed by setup_inputs)
constexpr int NN = 2;       // batch
constexpr int LL = 2048;    // sequence
constexpr int HH = 8;       // heads
constexpr int EE = 32;      // feature dim == value dim
constexpr int CC = 64;      // chunk length
constexpr int NCH = LL / CC;       // 32 chunks per (n,h)
constexpr int BWD = 10;     // softmax bandwidth
constexpr float EPSF = 1e-6f;
// ws record per chunk: S1[32*32], k1[32], S2[32*32], k2[32] (floats)
constexpr int REC = 2 * (EE * EE + EE);   // 2112
constexpr int OFF_S1 = 0, OFF_K1 = 1024, OFF_S2 = 1056, OFF_K2 = 2080;

__device__ __forceinline__ float elu1(float x) {
    // elu(x)+1 = x+1 (x>0) else exp(x)
    return x > 0.f ? x + 1.f : __expf(x);
}

// ---------------- Kernel 1: per-chunk sums of normalized-K outer products -----
// block = 256, one block per (n,h,chunk); grid = NN*HH*NCH = 512
__global__ __launch_bounds__(256) void chunksum_kernel(
    const float* __restrict__ Kin, const float* __restrict__ Vin,
    const float* __restrict__ KLin, float* __restrict__ ws)
{
    __shared__ float K1n[CC][EE + 1];
    __shared__ float K2n[CC][EE + 1];
    __shared__ float Vs [CC][EE + 1];

    const int b  = blockIdx.x;
    const int c  = b % NCH;
    const int nh = b / NCH;     // n*HH + h
    const int t  = threadIdx.x;
    const int lane = t & 31;
    const int grp  = t >> 5;    // 0..7

    // phase 1: feature-map + normalize rows (half-wave per row)
    for (int r = grp; r < CC; r += 8) {
        const int l = c * CC + r;
        const int base = ((nh / HH) * LL + l) * HH * EE + (nh % HH) * EE + lane;
        const float k    = Kin[base];
        const float v    = Vin[base];
        const float klen = KLin[(nh / HH) * LL + l];
        const float f1 = elu1(k);
        const float k1v = f1 * klen;
        const float k2v = f1 * f1 * klen;
        float s1 = k1v, s2 = k2v;
        #pragma unroll
        for (int m = 1; m < 32; m <<= 1) {
            s1 += __shfl_xor(s1, m, 32);
            s2 += __shfl_xor(s2, m, 32);
        }
        K1n[r][lane] = k1v / s1;
        K2n[r][lane] = k2v / s2;
        Vs [r][lane] = v;
    }
    __syncthreads();

    // phase 2: S[e][d] = sum_j K[j][e] * V[j][d]; thread = (e, 4 d's)
    const int e  = t & 31;
    const int dg = t >> 5;      // 0..7 -> d = dg*4 + i
    float a1[4] = {0.f, 0.f, 0.f, 0.f};
    float a2[4] = {0.f, 0.f, 0.f, 0.f};
    float ks1 = 0.f, ks2 = 0.f;
    for (int j = 0; j < CC; ++j) {
        const float k1 = K1n[j][e];
        const float k2 = K2n[j][e];
        ks1 += k1; ks2 += k2;
        #pragma unroll
        for (int i = 0; i < 4; ++i) {
            const float v = Vs[j][dg * 4 + i];
            a1[i] += k1 * v;
            a2[i] += k2 * v;
        }
    }
    float* wb = ws + (size_t)b * REC;
    #pragma unroll
    for (int i = 0; i < 4; ++i) {
        wb[OFF_S1 + e * EE + dg * 4 + i] = a1[i];
        wb[OFF_S2 + e * EE + dg * 4 + i] = a2[i];
    }
    if (dg == 0) {
        wb[OFF_K1 + e] = ks1;
        wb[OFF_K2 + e] = ks2;
    }
}

// ---------------- Kernel 2: exclusive prefix over chunks per (n,h) -----------
// grid = NN*HH = 16 blocks, 256 threads
__global__ __launch_bounds__(256) void prefix_kernel(float* __restrict__ ws)
{
    const size_t base = (size_t)blockIdx.x * NCH * REC;
    for (int i = threadIdx.x; i < REC; i += 256) {
        float run = 0.f;
        for (int c = 0; c < NCH; ++c) {
            const size_t idx = base + (size_t)c * REC + i;
            const float v = ws[idx];
            ws[idx] = run;
            run += v;
        }
    }
}

// ---------------- Kernel 3: banded softmax attention, writes out = W1*SV -----
// half-wave (32 lanes) per row; block 256 -> 8 rows; grid = NN*LL*HH/8 = 4096
__global__ __launch_bounds__(256) void band_kernel(
    const float* __restrict__ Qin, const float* __restrict__ Kin,
    const float* __restrict__ Vin, const float* __restrict__ W1,
    float* __restrict__ out)
{
    const int t    = threadIdx.x;
    const int lane = t & 31;
    const int g    = blockIdx.x * 8 + (t >> 5);  // (n*LL + l)*HH + h
    const int h    = g % HH;
    const int nl   = g / HH;
    const int l    = nl % LL;
    const int n    = nl / LL;

    const float temp = 0.17677669529663687f;   // 1/sqrt(32)
    const float q = Qin[g * EE + lane];

    float sarr[BWD];
    const int j0 = l - (BWD - 1);
    #pragma unroll
    for (int jj = 0; jj < BWD; ++jj) {
        const int j = j0 + jj;
        float s = -INFINITY;
        if (j >= 0) {
            float p = q * Kin[((n * LL + j) * HH + h) * EE + lane];
            #pragma unroll
            for (int m = 1; m < 32; m <<= 1) p += __shfl_xor(p, m, 32);
            s = p * temp;
        }
        sarr[jj] = s;
    }
    float mx = -INFINITY;
    #pragma unroll
    for (int jj = 0; jj < BWD; ++jj) mx = fmaxf(mx, sarr[jj]);
    float sum = 0.f;
    #pragma unroll
    for (int jj = 0; jj < BWD; ++jj) {
        const int j = j0 + jj;
        float p = (j >= 0) ? __expf(sarr[jj] - mx) : 0.f;
        sarr[jj] = p;
        sum += p;
    }
    const float inv = 1.f / sum;
    float sv = 0.f;
    #pragma unroll
    for (int jj = 0; jj < BWD; ++jj) {
        const int j = j0 + jj;
        if (j >= 0) sv += sarr[jj] * Vin[((n * LL + j) * HH + h) * EE + lane];
    }
    out[g * EE + lane] = W1[h * EE + lane] * (sv * inv);
}

// ---------------- Kernel 4: chunked causal linear attention, out += ... ------
// one block per (n,h,chunk); 256 threads = 4 threads per row (8 d's each)
__global__ __launch_bounds__(256) void linear_kernel(
    const float* __restrict__ Qin, const float* __restrict__ Kin,
    const float* __restrict__ Vin, const float* __restrict__ KLin,
    const float* __restrict__ W2, const float* __restrict__ W3,
    const float* __restrict__ ws, float* __restrict__ out)
{
    __shared__ float Q1n[CC][EE + 1];   // +1 pad: kills 16-way bank alias on [r][e] reads
    __shared__ float Q2n[CC][EE + 1];
    __shared__ float K1n[CC][EE + 1];
    __shared__ float K2n[CC][EE + 1];
    __shared__ float Vs [CC][EE + 1];
    __shared__ float S1p[EE * EE];
    __shared__ float S2p[EE * EE];
    __shared__ float k1p[EE];
    __shared__ float k2p[EE];

    const int b  = blockIdx.x;
    const int c  = b % NCH;
    const int nh = b / NCH;
    const int h  = nh % HH;
    const int n  = nh / HH;
    const int t  = threadIdx.x;

    // load exclusive-prefix state for this chunk
    const float* wb = ws + (size_t)b * REC;
    for (int i = t; i < EE * EE; i += 256) {
        S1p[i] = wb[OFF_S1 + i];
        S2p[i] = wb[OFF_S2 + i];
    }
    if (t < EE) {
        k1p[t] = wb[OFF_K1 + t];
        k2p[t] = wb[OFF_K2 + t];
    }

    // feature maps + normalization (half-wave per row)
    const int lane = t & 31;
    const int grp  = t >> 5;
    for (int r = grp; r < CC; r += 8) {
        const int l = c * CC + r;
        const int base = ((n * LL + l) * HH + h) * EE + lane;
        const float q    = Qin[base];
        const float k    = Kin[base];
        const float v    = Vin[base];
        const float klen = KLin[n * LL + l];
        const float f1q = elu1(q);
        const float f1k = elu1(k);
        const float q2v = f1q * f1q;
        const float k1v = f1k * klen;
        const float k2v = f1k * f1k * klen;
        float sq1 = f1q, sq2 = q2v, sk1 = k1v, sk2 = k2v;
        #pragma unroll
        for (int m = 1; m < 32; m <<= 1) {
            sq1 += __shfl_xor(sq1, m, 32);
            sq2 += __shfl_xor(sq2, m, 32);
            sk1 += __shfl_xor(sk1, m, 32);
            sk2 += __shfl_xor(sk2, m, 32);
        }
        Q1n[r][lane] = f1q / sq1;
        Q2n[r][lane] = q2v / sq2;
        K1n[r][lane] = k1v / sk1;
        K2n[r][lane] = k2v / sk2;
        Vs [r][lane] = v;
    }
    __syncthreads();

    // 4 threads per row; sub handles d in [sub*8, sub*8+8)
    const int r   = t >> 2;
    const int sub = t & 3;
    const int d0  = sub * 8;

    float acc1[8], acc2[8];
    #pragma unroll
    for (int dd = 0; dd < 8; ++dd) { acc1[dd] = 0.f; acc2[dd] = 0.f; }
    float den1 = 0.f, den2 = 0.f;

    // prefix contribution: Qn_r @ S_pre and Qn_r . k_pre
    for (int e = 0; e < EE; ++e) {
        const float q1 = Q1n[r][e];
        const float q2 = Q2n[r][e];
        den1 += q1 * k1p[e];
        den2 += q2 * k2p[e];
        #pragma unroll
        for (int dd = 0; dd < 8; ++dd) {
            acc1[dd] += q1 * S1p[e * EE + d0 + dd];
            acc2[dd] += q2 * S2p[e * EE + d0 + dd];
        }
    }

    // hoist this row's Q fragment (loop-invariant in j)
    float q1r[8], q2r[8];
    #pragma unroll
    for (int i = 0; i < 8; ++i) {
        q1r[i] = Q1n[r][d0 + i];
        q2r[i] = Q2n[r][d0 + i];
    }

    // intra-chunk causal: dot over e split across 4 subs, reduced via shfl(w=4)
    for (int j = 0; j <= r; ++j) {
        float p1 = 0.f, p2 = 0.f;
        #pragma unroll
        for (int i = 0; i < 8; ++i) {
            p1 += q1r[i] * K1n[j][d0 + i];
            p2 += q2r[i] * K2n[j][d0 + i];
        }
        p1 += __shfl_xor(p1, 1, 4); p1 += __shfl_xor(p1, 2, 4);
        p2 += __shfl_xor(p2, 1, 4); p2 += __shfl_xor(p2, 2, 4);
        den1 += p1;
        den2 += p2;
        #pragma unroll
        for (int dd = 0; dd < 8; ++dd) {
            const float v = Vs[j][d0 + dd];
            acc1[dd] += p1 * v;
            acc2[dd] += p2 * v;
        }
    }

    const float z1 = 1.f / (den1 + EPSF);
    const float z2 = 1.f / (den2 + EPSF);
    const int l = c * CC + r;
    const int ob = ((n * LL + l) * HH + h) * EE + d0;
    #pragma unroll
    for (int dd = 0; dd < 8; ++dd) {
        const int d = d0 + dd;
        out[ob + dd] += W2[h * EE + d] * acc1[dd] * z1
                      + W3[h * EE + d] * acc2[dd] * z2;
    }
}

extern "C" void kernel_launch(void* const* d_in, const int* in_sizes, int n_in,
                              void* d_out, int out_size, void* d_ws, size_t ws_size,
                              hipStream_t stream)
{
    const float* Q  = (const float*)d_in[0];
    const float* K  = (const float*)d_in[1];
    const float* V  = (const float*)d_in[2];
    const float* KL = (const float*)d_in[3];
    const float* W1 = (const float*)d_in[4];
    const float* W2 = (const float*)d_in[5];
    const float* W3 = (const float*)d_in[6];
    float* out = (float*)d_out;
    float* ws  = (float*)d_ws;   // needs NN*HH*NCH*REC*4 = ~4.3 MB

    // band first: it OVERWRITES every output element (erases 0xAA poison);
    // linear_kernel then does read-modify-write adds. Same stream => ordered.
    band_kernel    <<<(NN * LL * HH) / 8, 256, 0, stream>>>(Q, K, V, W1, out);
    chunksum_kernel<<<NN * HH * NCH,      256, 0, stream>>>(K, V, KL, ws);
    prefix_kernel  <<<NN * HH,            256, 0, stream>>>(ws);
    linear_kernel  <<<NN * HH * NCH,      256, 0, stream>>>(Q, K, V, KL, W2, W3, ws, out);
}